// Round 8
// baseline (12167.733 us; speedup 1.0000x reference)
//
#include <hip/hip_runtime.h>
#include <math.h>

#define BDIM 32
#define NDIM 512
#define FDIM 256
#define HDIM 1024
#define EDIM 8192
#define PCH  8192      // stein chunk: (b,j) pairs per pass; 2 passes (fu+fm in A, f1 in X1)
#define CLTH 1.2e-4f   // eigenvalue cluster threshold for MGS
#define NB   16        // backt WY panel width
#define TNB  32        // tridiag panel width
#define BCOLS 16       // backt slab columns

__device__ __forceinline__ float waveRedSum(float v){
#pragma unroll
  for(int o=32;o>0;o>>=1) v += __shfl_down(v,o,64);
  return v;
}

__device__ __forceinline__ float rnd_f(int g, int i){
  unsigned s = (unsigned)g*1315423911u ^ (unsigned)i*2654435761u;
  s ^= s>>13; s *= 2246822519u; s ^= s>>16;
  return (float)(s & 0xFFFF)*(1.f/65536.f) - 0.5f;
}

// ---------------- int64-vs-int32 edge index layout detection ----------------
__global__ __launch_bounds__(1024) void k_detect(const unsigned* __restrict__ e, int* __restrict__ flag){
  int t = threadIdx.x;
  float c = 0.f;
  for(int i=t;i<EDIM;i+=1024) if(e[2*i+1] != 0u) c += 1.f;
  c = waveRedSum(c);
  __shared__ float r[16];
  if((t&63)==0) r[t>>6]=c;
  __syncthreads();
  if(t==0){ float s=0; for(int z=0;z<16;z++) s+=r[z]; flag[0] = (s>64.f)?1:0; }
}

// ---------------- Laplacian assembly ----------------
__global__ __launch_bounds__(256) void k_scatter(const float* __restrict__ ew, const int* __restrict__ eidx,
                                                 const int* __restrict__ flag, float* __restrict__ A){
  int t = blockIdx.x*256 + threadIdx.x;           // B*E threads
  int b = t>>13, e = t&(EDIM-1);
  int i, j;
  if(flag[0]){ i = eidx[e]; j = eidx[EDIM+e]; }
  else       { i = eidx[2*e]; j = eidx[2*(EDIM+e)]; }  // little-endian int64 low words
  i &= 511; j &= 511;
  float w = ew[(size_t)b*EDIM + e];
  w = 0.5f*fminf(fmaxf(w,0.f),1.f);               // clip then build (A+A^T)/2 directly
  float* Ab = A + (size_t)b*NDIM*NDIM;
  atomicAdd(Ab + (size_t)i*NDIM + j, w);
  atomicAdd(Ab + (size_t)j*NDIM + i, w);
}

__global__ __launch_bounds__(256) void k_degree(const float* __restrict__ A, float* __restrict__ dis){
  int wid = threadIdx.x>>6, lane = threadIdx.x&63;
  int row = blockIdx.x*4 + wid;                   // b*N + i
  const float* Ar = A + (size_t)row*NDIM;
  float s = 0.f;
  for(int j=lane;j<NDIM;j+=64) s += Ar[j];
  s = waveRedSum(s);
  if(lane==0) dis[row] = rsqrtf(fmaxf(s, 1e-6f));
}

__global__ __launch_bounds__(256) void k_lap(float* __restrict__ A, const float* __restrict__ dis){
  size_t t = (size_t)blockIdx.x*256 + threadIdx.x;   // B*N*N
  size_t nn = (size_t)NDIM*NDIM;
  int b = (int)(t / nn); size_t rem = t % nn;
  int i = (int)(rem / NDIM), j = (int)(rem % NDIM);
  float v = -dis[b*NDIM+i]*dis[b*NDIM+j]*A[t];
  if(i==j) v += 1.f + 1e-6f;
  A[t] = v;
}

// ---------------- LayerNorm (stores pre-relu x; relu applied at GEMM load) ----------------
__global__ __launch_bounds__(256) void k_ln(const float* __restrict__ nf, const float* __restrict__ g,
                                            const float* __restrict__ be, float* __restrict__ X){
  int wid = threadIdx.x>>6, lane = threadIdx.x&63;
  int row = blockIdx.x*4 + wid;                   // b*N + n
  const float4* r4 = (const float4*)(nf + (size_t)row*FDIM);
  float4 v = r4[lane];
  float s  = v.x+v.y+v.z+v.w;
  float s2 = v.x*v.x+v.y*v.y+v.z*v.z+v.w*v.w;
  s = waveRedSum(s); s2 = waveRedSum(s2);
  s = __shfl(s,0,64); s2 = __shfl(s2,0,64);
  float mean = s*(1.f/FDIM);
  float var  = s2*(1.f/FDIM) - mean*mean;
  float inv  = rsqrtf(var + 1e-5f);
  float4 gg = ((const float4*)g)[lane];
  float4 bb = ((const float4*)be)[lane];
  float4 o;
  o.x = (v.x-mean)*inv*gg.x + bb.x;
  o.y = (v.y-mean)*inv*gg.y + bb.y;
  o.z = (v.z-mean)*inv*gg.z + bb.z;
  o.w = (v.w-mean)*inv*gg.w + bb.w;
  ((float4*)(X + (size_t)row*FDIM))[lane] = o;
}

// ---------------- LATRD-blocked Householder tridiagonalization (1 block / matrix, 512 thr) ----------------
// TNB=32 panels: 16 trailing sweeps total (halved RMW traffic); 8x4 update tiles.
__global__ __launch_bounds__(512,1) void k_tridiag(float* __restrict__ A, float* __restrict__ U,
                                                   float* __restrict__ dia, float* __restrict__ off,
                                                   float* __restrict__ tau){
  const int b = blockIdx.x, t = threadIdx.x;
  float* Ab = A + (size_t)b*NDIM*NDIM;
  float* Ub = U + (size_t)b*NDIM*NDIM;
  __shared__ __align__(16) float Up[TNB][NDIM];   // 64KB
  __shared__ __align__(16) float Wp[TNB][NDIM];   // 64KB
  __shared__ __align__(16) float ps[4][NDIM];     // 8KB symv row-group partials
  __shared__ float dW[TNB], dU[TNB];
  __shared__ float sig_s, pd_s, x0_s;
  const int lane = t&63;
  const int cc = t&127, rg = t>>7;                // 128 col-chunks x 4 row-groups
  if(t==0){ sig_s = 0.f; pd_s = 0.f; }

  for(int k0=0; k0<NDIM-2; k0+=TNB){
    const int ne = (TNB < NDIM-2-k0)? TNB : (NDIM-2-k0);
    for(int q=0;q<TNB;q++){ Up[q][t]=0.f; Wp[q][t]=0.f; }
    __syncthreads();
    for(int p=0;p<ne;p++){
      const int k = k0+p;
      // ---- step 1: virtual row k + partial sigma (LDS atomic) ----
      float v = 0.f;
      if(t>k){
        v = Ab[(size_t)k*NDIM + t];
        for(int q=0;q<p;q++) v -= Up[q][k]*Wp[q][t] + Wp[q][k]*Up[q][t];
      }
      if(t<TNB){ dW[t]=0.f; dU[t]=0.f; }
      if(t==0) pd_s = 0.f;
      if(t==k+1) x0_s = v;
      float ssq = (t>=k+2)? v*v : 0.f;
      ssq = waveRedSum(ssq);
      if(lane==0) atomicAdd(&sig_s, ssq);
      __syncthreads();                               // B1: sigma & x0 ready
      const float sigma = sig_s, x0 = x0_s;
      float tk = 0.f, inv = 0.f, beta = x0;          // all threads compute redundantly
      if(sigma > 1e-26f){
        beta = -copysignf(sqrtf(x0*x0+sigma), x0);
        tk = (beta-x0)/beta; inv = 1.f/(x0-beta);
      }
      const float u_t = (t>=k+2)? v*inv : ((t==k+1 && sigma>1e-26f)? 1.f : 0.f);
      Up[p][t] = u_t;
      // panel dots fused here (use register u_t)
      for(int q=0;q<p;q++){
        float pw = waveRedSum(Wp[q][t]*u_t);
        float pu = waveRedSum(Up[q][t]*u_t);
        if(lane==0){ atomicAdd(&dW[q],pw); atomicAdd(&dU[q],pu); }
      }
      __syncthreads();                               // B2: u + dots ready
      if(t==0) sig_s = 0.f;                          // safe: all read sigma before B2
      // ---- symv py[j] = sum_i A[i][j] u[i]; 32-row super-iters, 8 loads in flight + 1-ahead ----
      {
        float4 acc = {0.f,0.f,0.f,0.f};
        const int j0 = 4*cc;
        if(j0+3 > k){
          const float* basep = Ab + j0;
          const int ib0 = (k+1)&~31;                 // u[i]==0 for i<=k -> boundary-free
          const int i1 = rg*4, i2 = 16+rg*4;
          const float* ap = basep + (size_t)ib0*NDIM;
          float4 c0 = *(const float4*)(ap + (size_t)(i1  )*NDIM);
          float4 c1 = *(const float4*)(ap + (size_t)(i1+1)*NDIM);
          float4 c2 = *(const float4*)(ap + (size_t)(i1+2)*NDIM);
          float4 c3 = *(const float4*)(ap + (size_t)(i1+3)*NDIM);
          float4 d0 = *(const float4*)(ap + (size_t)(i2  )*NDIM);
          float4 d1 = *(const float4*)(ap + (size_t)(i2+1)*NDIM);
          float4 d2 = *(const float4*)(ap + (size_t)(i2+2)*NDIM);
          float4 d3 = *(const float4*)(ap + (size_t)(i2+3)*NDIM);
          for(int ib=ib0; ib<NDIM; ib+=32){
            float4 n0=c0,n1=c1,n2=c2,n3=c3,m0=d0,m1=d1,m2=d2,m3=d3;
            if(ib+32 < NDIM){
              const float* an = basep + (size_t)(ib+32)*NDIM;
              n0 = *(const float4*)(an + (size_t)(i1  )*NDIM);
              n1 = *(const float4*)(an + (size_t)(i1+1)*NDIM);
              n2 = *(const float4*)(an + (size_t)(i1+2)*NDIM);
              n3 = *(const float4*)(an + (size_t)(i1+3)*NDIM);
              m0 = *(const float4*)(an + (size_t)(i2  )*NDIM);
              m1 = *(const float4*)(an + (size_t)(i2+1)*NDIM);
              m2 = *(const float4*)(an + (size_t)(i2+2)*NDIM);
              m3 = *(const float4*)(an + (size_t)(i2+3)*NDIM);
            }
            float4 u1 = *(const float4*)&Up[p][ib+i1];
            float4 u2 = *(const float4*)&Up[p][ib+i2];
            acc.x += c0.x*u1.x + c1.x*u1.y + c2.x*u1.z + c3.x*u1.w
                   + d0.x*u2.x + d1.x*u2.y + d2.x*u2.z + d3.x*u2.w;
            acc.y += c0.y*u1.x + c1.y*u1.y + c2.y*u1.z + c3.y*u1.w
                   + d0.y*u2.x + d1.y*u2.y + d2.y*u2.z + d3.y*u2.w;
            acc.z += c0.z*u1.x + c1.z*u1.y + c2.z*u1.z + c3.z*u1.w
                   + d0.z*u2.x + d1.z*u2.y + d2.z*u2.z + d3.z*u2.w;
            acc.w += c0.w*u1.x + c1.w*u1.y + c2.w*u1.z + c3.w*u1.w
                   + d0.w*u2.x + d1.w*u2.y + d2.w*u2.z + d3.w*u2.w;
            c0=n0; c1=n1; c2=n2; c3=n3; d0=m0; d1=m1; d2=m2; d3=m3;
          }
        }
        *(float4*)&ps[rg][4*cc] = acc;
      }
      __syncthreads();                               // B3: ps ready
      float py = ps[0][t]+ps[1][t]+ps[2][t]+ps[3][t];
      float corr = 0.f;
      for(int q=0;q<p;q++) corr += Up[q][t]*dW[q] + Wp[q][t]*dU[q];
      float pv = tk*(py - corr);
      float pdp = waveRedSum(pv*u_t);
      if(lane==0) atomicAdd(&pd_s, pdp);
      __syncthreads();                               // B4: pd ready
      float hh = 0.5f*tk*pd_s;
      float w_t = (t>k)? (pv - hh*u_t) : 0.f;
      Wp[p][t] = w_t;
      if(t>k) Ub[(size_t)k*NDIM + (t-k-1)] = u_t;
      if(t==0){
        off[(size_t)b*NDIM+k] = beta; tau[(size_t)b*NDIM+k] = tk;
        float dk = Ab[(size_t)k*NDIM+k];
        for(int q=0;q<p;q++) dk -= 2.f*Up[q][k]*Wp[q][k];
        dia[(size_t)b*NDIM+k]=dk;
      }
      __syncthreads();                               // B5: w ready for next column
    }
    // ---- trailing rank-2*ne update: 8x4 tiles, 16 sweeps total ----
    {
      const int r0 = k0+ne;
      const int rbase = r0 & ~31;                 // extra rows/cols never read again
      const int cstart = rbase>>2;
      if(cc >= cstart){
        const int j0 = 4*cc;
        for(int rt=rbase; rt<NDIM; rt+=32){
          const int i0 = rt + rg*8;
          float* a0 = Ab + (size_t)i0*NDIM + j0;
          float4 v[8];
          #pragma unroll
          for(int r=0;r<8;r++) v[r] = *(float4*)(a0 + (size_t)r*NDIM);
          #pragma unroll 4
          for(int q=0;q<ne;q++){
            float4 Uj = *(const float4*)&Up[q][j0];
            float4 Wj = *(const float4*)&Wp[q][j0];
            float4 ua = *(const float4*)&Up[q][i0];
            float4 ub = *(const float4*)&Up[q][i0+4];
            float4 wa = *(const float4*)&Wp[q][i0];
            float4 wb = *(const float4*)&Wp[q][i0+4];
            float ui[8]={ua.x,ua.y,ua.z,ua.w,ub.x,ub.y,ub.z,ub.w};
            float wi[8]={wa.x,wa.y,wa.z,wa.w,wb.x,wb.y,wb.z,wb.w};
            #pragma unroll
            for(int r=0;r<8;r++){
              v[r].x -= ui[r]*Wj.x + wi[r]*Uj.x;
              v[r].y -= ui[r]*Wj.y + wi[r]*Uj.y;
              v[r].z -= ui[r]*Wj.z + wi[r]*Uj.z;
              v[r].w -= ui[r]*Wj.w + wi[r]*Uj.w;
            }
          }
          #pragma unroll
          for(int r=0;r<8;r++) *(float4*)(a0 + (size_t)r*NDIM) = v[r];
        }
      }
    }
    __syncthreads();
  }
  if(t==0){
    dia[(size_t)b*NDIM+NDIM-2] = Ab[(size_t)(NDIM-2)*NDIM+NDIM-2];
    dia[(size_t)b*NDIM+NDIM-1] = Ab[(size_t)(NDIM-1)*NDIM+NDIM-1];
    off[(size_t)b*NDIM+NDIM-2] = Ab[(size_t)(NDIM-2)*NDIM+NDIM-1];
    off[(size_t)b*NDIM+NDIM-1] = 0.f;
    tau[(size_t)b*NDIM+NDIM-2]=0.f; tau[(size_t)b*NDIM+NDIM-1]=0.f;
  }
}

// ---------------- eigenvalues: Sturm bisection (thread j -> j-th smallest) ----------------
__global__ __launch_bounds__(512) void k_bisect(const float* __restrict__ dia, const float* __restrict__ off,
                                                float* __restrict__ lam){
  int b = blockIdx.x, t = threadIdx.x;
  __shared__ float ds[NDIM], e2[NDIM];
  __shared__ float red[16];
  __shared__ float slo, shi;
  ds[t] = dia[(size_t)b*NDIM+t];
  float ev = (t<NDIM-1)? off[(size_t)b*NDIM+t] : 0.f;
  e2[t] = ev*ev;
  __syncthreads();
  float el = (t>0)? sqrtf(e2[t-1]) : 0.f;
  float er = fabsf(ev);
  float lo = ds[t]-el-er, hi = ds[t]+el+er;
#pragma unroll
  for(int o=32;o>0;o>>=1){ lo = fminf(lo,__shfl_down(lo,o,64)); hi = fmaxf(hi,__shfl_down(hi,o,64)); }
  if((t&63)==0){ red[t>>6]=lo; red[8+(t>>6)]=hi; }
  __syncthreads();
  if(t==0){
    float L=red[0], H=red[8];
    for(int z=1;z<8;z++){ L=fminf(L,red[z]); H=fmaxf(H,red[8+z]); }
    slo = L-1e-3f; shi = H+1e-3f;
  }
  __syncthreads();
  float lo2 = slo, hi2 = shi;
  for(int it=0; it<30; ++it){
    float mid = 0.5f*(lo2+hi2);
    float q = ds[0]-mid; int c = (q<0.f)?1:0;
    for(int i=1;i<NDIM;i++){
      float dn = (fabsf(q)<1e-10f)? ((q<0.f)?-1e-10f:1e-10f) : q;
      q = ds[i]-mid - __fdividef(e2[i-1], dn);
      c += (q<0.f)?1:0;
    }
    if(c<=t) lo2=mid; else hi2=mid;
  }
  lam[(size_t)b*NDIM+t] = 0.5f*(lo2+hi2);
}

// ---------------- eigenvectors of T: inverse iteration; fu+fm in fac, s1 in xs ----------------
__global__ __launch_bounds__(64) void k_stein(const float* __restrict__ dia, const float* __restrict__ off,
                                              const float* __restrict__ lam, float* __restrict__ W,
                                              float* __restrict__ fac, float* __restrict__ xs, int chunk){
  int p = blockIdx.x*64 + threadIdx.x;            // 0..PCH-1
  int g = chunk*PCH + p;                           // global (b,j)
  int b = g >> 9, j = g & 511;
  __shared__ float ds[NDIM], es[NDIM];
  for(int i=threadIdx.x;i<NDIM;i+=64){ ds[i]=dia[(size_t)b*NDIM+i]; es[i]=off[(size_t)b*NDIM+i]; }
  __syncthreads();
  float lm = lam[(size_t)b*NDIM+j] + (float)((j%5)-2)*1.2e-7f;   // tiny split of identical shifts
  float* fu = fac + p;                              // reciprocal pivots 1/u
  float* fm = fac + (size_t)PCH*NDIM + p;           // mm encoded: +3.0 if row-swapped (|mm|<=1)
  float* f1a = xs + p;                              // s1 (running superdiag / an on swap)
  // ---- factor (T - lm I) = P L U, partial pivoting ----
  float ai = ds[0]-lm, bi = es[0];
  for(int ib=0; ib<NDIM-1; ib+=8){
    const int lim = (NDIM-1-ib < 8)? NDIM-1-ib : 8;
    float dsb[8], esb[8], enb[8];
    #pragma unroll
    for(int z=0;z<8;z++){
      int i = ib+z; bool vz = z<lim;
      dsb[z] = vz? ds[i+1] : 0.f;
      esb[z] = vz? es[i]   : 0.f;
      enb[z] = (vz && i<NDIM-2)? es[i+1] : 0.f;
    }
    #pragma unroll
    for(int z=0;z<8;z++){
      if(z<lim){
        int i = ib+z;
        float ci = esb[z], an = dsb[z]-lm, bn = enb[z];
        float uu, mmenc, s1;
        if(fabsf(ai) >= fabsf(ci)){
          float aa = (fabsf(ai)<1e-12f)? ((ai<0.f)?-1e-12f:1e-12f) : ai;
          float mm = __fdividef(ci, aa);
          uu=aa; mmenc=mm; s1=bi;
          ai = an - mm*bi; bi = bn;
        } else {
          float cch = (fabsf(ci)<1e-12f)? ((ci<0.f)?-1e-12f:1e-12f) : ci;
          float mm = __fdividef(ai, cch);
          uu=cch; mmenc=mm+3.f; s1=an;
          ai = bi - mm*an; bi = -mm*bn;
        }
        fu[(size_t)i*PCH]=__fdividef(1.f,uu);
        fm[(size_t)i*PCH]=mmenc;
        f1a[(size_t)i*PCH]=s1;
      }
    }
  }
  { float aa = (fabsf(ai)<1e-12f)? ((ai<0.f)?-1e-12f:1e-12f) : ai; fu[(size_t)(NDIM-1)*PCH]=__fdividef(1.f,aa); }
  float* Wb = W + (size_t)b*NDIM*NDIM + j;         // element i at Wb[i*NDIM]
  float scale = 1.f;
  for(int it=0; it<3; ++it){
    // ---- forward substitution, 8-deep prefetch ----
    float yi = (it==0)? rnd_f(g,0) : Wb[0]*scale;
    for(int ib=0; ib<NDIM-1; ib+=8){
      const int lim = (NDIM-1-ib < 8)? NDIM-1-ib : 8;
      float wn[8], me[8];
      #pragma unroll
      for(int z=0;z<8;z++){
        int i = ib+z; bool vz = z<lim;
        wn[z] = vz? ((it==0)? rnd_f(g,i+1) : Wb[(size_t)(i+1)*NDIM]*scale) : 0.f;
        me[z] = vz? fm[(size_t)i*PCH] : 0.f;
      }
      #pragma unroll
      for(int z=0;z<8;z++){
        if(z<lim){
          int i = ib+z;
          float enc = me[z]; bool sw = enc>1.5f; float mm = sw? enc-3.f : enc;
          float yn = wn[z];
          if(sw){ float tmp=yi; yi=yn; yn=tmp; }
          yn -= mm*yi;
          Wb[(size_t)i*NDIM] = yi;
          yi = yn;
        }
      }
    }
    // ---- backward substitution (division-free; f1 stored, f2 from flag) ----
    float nrm, xp1, xp2;
    {
      float xi = yi * fu[(size_t)(NDIM-1)*PCH];
      Wb[(size_t)(NDIM-1)*NDIM]=xi; nrm = xi*xi; xp2=0.f; xp1=xi;
    }
    for(int ib=NDIM-2; ib>=0; ib-=8){
      const int lim = (ib+1 < 8)? ib+1 : 8;
      float yv[8], ru[8], me[8], f1b[8];
      #pragma unroll
      for(int z=0;z<8;z++){
        int i = ib-z; bool vz = z<lim;
        yv[z]  = vz? Wb[(size_t)i*NDIM] : 0.f;
        ru[z]  = vz? fu[(size_t)i*PCH] : 0.f;
        me[z]  = vz? fm[(size_t)i*PCH] : 0.f;
        f1b[z] = vz? f1a[(size_t)i*PCH] : 0.f;
      }
      #pragma unroll
      for(int z=0;z<8;z++){
        if(z<lim){
          int i = ib-z;
          bool sw = me[z]>1.5f;
          float f2 = sw? ((i<NDIM-2)? es[i+1] : 0.f) : 0.f;
          float xi = (yv[z] - f1b[z]*xp1 - f2*xp2)*ru[z];
          Wb[(size_t)i*NDIM]=xi; nrm += xi*xi;
          xp2=xp1; xp1=xi;
        }
      }
    }
    scale = rsqrtf(fmaxf(nrm,1e-30f));
  }
  for(int ib=0; ib<NDIM; ib+=8){
    float vz[8];
    #pragma unroll
    for(int z=0;z<8;z++) vz[z] = Wb[(size_t)(ib+z)*NDIM];
    #pragma unroll
    for(int z=0;z<8;z++) Wb[(size_t)(ib+z)*NDIM] = vz[z]*scale;
  }
}

// ---------------- MGS inside eigenvalue clusters ----------------
__global__ __launch_bounds__(512) void k_mgs(const float* __restrict__ lam, float* __restrict__ W){
  int b = blockIdx.x, t = threadIdx.x;
  __shared__ int cstart[NDIM];
  __shared__ unsigned char brk[NDIM];
  __shared__ float red[8];
  __shared__ float sbc;
  const float* lb = lam + (size_t)b*NDIM;
  float* Wb = W + (size_t)b*NDIM*NDIM;
  brk[t] = (t==0)? 1 : ((lb[t]-lb[t-1] > CLTH)? 1 : 0);
  __syncthreads();
  if(t==0){ int s=0; for(int j=0;j<NDIM;j++){ if(brk[j]) s=j; cstart[j]=s; } }
  __syncthreads();
  for(int j=1;j<NDIM;j++){
    int s = cstart[j];
    if(s==j) continue;                             // uniform branch
    for(int q=s;q<j;q++){
      float pd = 0.f;
      pd = Wb[(size_t)t*NDIM+q]*Wb[(size_t)t*NDIM+j];
      pd = waveRedSum(pd);
      if((t&63)==0) red[t>>6]=pd;
      __syncthreads();
      if(t==0){ float s2=0; for(int z=0;z<8;z++) s2+=red[z]; sbc=s2; }
      __syncthreads();
      float dt = sbc;
      Wb[(size_t)t*NDIM+j] -= dt*Wb[(size_t)t*NDIM+q];
      __syncthreads();
    }
    float v = Wb[(size_t)t*NDIM+j];
    float pn = waveRedSum(v*v);
    if((t&63)==0) red[t>>6]=pn;
    __syncthreads();
    if(t==0){ float s2=0; for(int z=0;z<8;z++) s2+=red[z]; sbc=s2; }
    __syncthreads();
    Wb[(size_t)t*NDIM+j] = v*rsqrtf(fmaxf(sbc,1e-20f));
    __syncthreads();
  }
}

// ---------------- back-transform Z = H0..H509 * W ; blocked LARFB (compact-WY), 16-col slabs ----------------
__global__ __launch_bounds__(512,4) void k_backt(float* __restrict__ W, const float* __restrict__ U,
                                                 const float* __restrict__ tau){
  __shared__ float S[NDIM][BCOLS+1];     // 34816 B
  __shared__ float Up[NB][516];          // 33024 B
  __shared__ float Gp[NB][NB+1];         // Gram v_s.v_j (s<j)
  __shared__ float Tm[NB][NB+1];         // T upper-triangular
  __shared__ float Yp[2][NB][NB+1];      // Y = V^T S partials
  __shared__ float Z16[NB][NB+1];        // Z = T Y
  __shared__ float tls[NB];
  const int t = threadIdx.x;
  int b = blockIdx.x >> 5, slab = blockIdx.x & 31;
  int c0 = slab*BCOLS;
  float* Wb = W + (size_t)b*NDIM*NDIM;
  const float* Ub = U + (size_t)b*NDIM*NDIM;
  for(int l=t; l<NDIM*BCOLS; l+=512){
    int i = l>>4, c = l&15;
    S[i][c] = Wb[(size_t)i*NDIM + c0 + c];
  }
  __syncthreads();
  for(int k0 = ((NDIM-3)/NB)*NB; k0>=0; k0-=NB){
    for(int l=t; l<NB*NDIM; l+=512){
      int q = l>>9, i = l&511;
      int k = k0+q;
      float v = 0.f;
      if(k < NDIM-2 && i > k) v = Ub[(size_t)k*NDIM + (i-k-1)];
      Up[q][i] = v;
    }
    if(t<NB) tls[t] = (k0+t < NDIM-2)? tau[(size_t)b*NDIM + k0 + t] : 0.f;
    if(t<NB*(NB+1)) ((float*)Gp)[t] = 0.f;
    __syncthreads();                                  // P1: V, tau ready; G zeroed
    if(t < 480){
      int pp = t>>2, sub = t&3;
      int pj=1, pr=pp;
      while(pr >= pj){ pr -= pj; pj++; }
      int s = pr, jj = pj;                            // s < jj, jj in 1..15
      float acc = 0.f;
      for(int i=k0+1+sub; i<NDIM; i+=4) acc += Up[s][i]*Up[jj][i];
      atomicAdd(&Gp[s][jj], acc);
    }
    __syncthreads();                                  // P2: G ready
    if(t < 16){
      int a = t;
      for(int j=0;j<NB;j++){
        float v;
        if(a==j) v = tls[j];
        else if(a<j){
          float s2 = 0.f;
          for(int s=a; s<j; s++) s2 += Tm[a][s]*Gp[s][j];
          v = -tls[j]*s2;
        } else v = 0.f;
        Tm[a][j] = v;
      }
    }
    __syncthreads();                                  // P3: T ready
    {
      int q=(t>>4)&15, c=t&15, half=t>>8;
      float a0=0.f, a1=0.f;
      int i = k0+1+half;
      for(; i+2<NDIM; i+=4){ a0 += Up[q][i]*S[i][c]; a1 += Up[q][i+2]*S[i+2][c]; }
      for(; i<NDIM; i+=2) a0 += Up[q][i]*S[i][c];
      Yp[half][q][c] = a0+a1;
    }
    __syncthreads();                                  // P4: Y ready
    if(t < 256){
      int a=t>>4, c=t&15;
      float acc=0.f;
      #pragma unroll
      for(int j=0;j<NB;j++) acc += Tm[a][j]*(Yp[0][j][c]+Yp[1][j][c]);
      Z16[a][c]=acc;
    }
    __syncthreads();                                  // P5: Z ready
    {
      int rg=t>>4, c=t&15;
      float zc[NB];
      #pragma unroll
      for(int q=0;q<NB;q++) zc[q]=Z16[q][c];
      for(int i=k0+1+rg; i<NDIM; i+=32){
        float s2=0.f;
        #pragma unroll
        for(int q=0;q<NB;q++) s2 += Up[q][i]*zc[q];
        S[i][c] -= s2;
      }
    }
    __syncthreads();                                  // P6: S updated; safe to reload V
  }
  for(int l=t; l<NDIM*BCOLS; l+=512){
    int i = l>>4, c = l&15;
    Wb[(size_t)i*NDIM + c0 + c] = S[i][c];
  }
}

// ---------------- eigenvalue MLP ----------------
__global__ __launch_bounds__(256) void k_mlp1(const float* __restrict__ lam, const float* __restrict__ w1,
                                              const float* __restrict__ b1, float* __restrict__ h){
  int wid = threadIdx.x>>6, lane = threadIdx.x&63;
  int j = blockIdx.x*4 + wid, b = blockIdx.y;
  const float* lb = lam + (size_t)b*NDIM;
  const float* wr = w1 + (size_t)j*NDIM;
  float acc = 0.f;
  for(int k=lane;k<NDIM;k+=64) acc += lb[k]*wr[k];
  acc = waveRedSum(acc);
  if(lane==0) h[(size_t)b*HDIM + j] = fmaxf(acc + b1[j], 0.f);
}
__global__ __launch_bounds__(256) void k_mlp2(const float* __restrict__ h, const float* __restrict__ w2,
                                              const float* __restrict__ b2, float* __restrict__ evb){
  int wid = threadIdx.x>>6, lane = threadIdx.x&63;
  int n = blockIdx.x*4 + wid, b = blockIdx.y;
  const float* hb = h + (size_t)b*HDIM;
  const float* wr = w2 + (size_t)n*HDIM;
  float acc = 0.f;
  for(int k=lane;k<HDIM;k+=64) acc += hb[k]*wr[k];
  acc = waveRedSum(acc);
  if(lane==0) evb[(size_t)b*NDIM + n] = acc + b2[n];
}

// ---------------- GEMM1: X1[i][f] = ev[i] * sum_n Z[n][i]*relu(X[n][f]) ----------------
__global__ __launch_bounds__(256) void k_gemm1(const float* __restrict__ Z, const float* __restrict__ X,
                                               const float* __restrict__ evb, float* __restrict__ X1){
  int b = blockIdx.z;
  int i0 = blockIdx.y*64, f0 = blockIdx.x*64;
  const float* Zb = Z + (size_t)b*NDIM*NDIM;
  const float* Xb = X + (size_t)b*NDIM*FDIM;
  __shared__ float As[32][65], Bs[32][65];
  int tx = threadIdx.x & 15, ty = threadIdx.x >> 4;
  float acc[4][4] = {};
  for(int n0=0;n0<NDIM;n0+=32){
    for(int l=threadIdx.x; l<32*64; l+=256){
      int dn = l>>6, dc = l&63;
      As[dn][dc] = Zb[(size_t)(n0+dn)*NDIM + i0+dc];
      Bs[dn][dc] = fmaxf(Xb[(size_t)(n0+dn)*FDIM + f0+dc], 0.f);
    }
    __syncthreads();
#pragma unroll
    for(int dn=0;dn<32;dn++){
      float a[4], bb[4];
#pragma unroll
      for(int z=0;z<4;z++){ a[z]=As[dn][ty*4+z]; bb[z]=Bs[dn][tx*4+z]; }
#pragma unroll
      for(int p=0;p<4;p++)
#pragma unroll
        for(int q=0;q<4;q++) acc[p][q] += a[p]*bb[q];
    }
    __syncthreads();
  }
#pragma unroll
  for(int p=0;p<4;p++){
    int i = i0 + ty*4 + p;
    float s = evb[(size_t)b*NDIM + i];
    float4 o = { acc[p][0]*s, acc[p][1]*s, acc[p][2]*s, acc[p][3]*s };
    *(float4*)(X1 + ((size_t)b*NDIM + i)*FDIM + f0 + tx*4) = o;
  }
}

// ---------------- GEMM2: out[n][f] = X[n][f] + sum_i Z[n][i]*X1[i][f] ----------------
__global__ __launch_bounds__(256) void k_gemm2(const float* __restrict__ Z, const float* __restrict__ X1,
                                               const float* __restrict__ X, float* __restrict__ outp){
  int b = blockIdx.z;
  int n0 = blockIdx.y*64, f0 = blockIdx.x*64;
  const float* Zb = Z + (size_t)b*NDIM*NDIM;
  const float* X1b = X1 + (size_t)b*NDIM*FDIM;
  __shared__ float As[32][65], Bs[32][65];
  int tx = threadIdx.x & 15, ty = threadIdx.x >> 4;
  float acc[4][4] = {};
  for(int i0=0;i0<NDIM;i0+=32){
    for(int l=threadIdx.x; l<32*64; l+=256){
      int di = l&31, dn = l>>5;
      As[di][dn] = Zb[(size_t)(n0+dn)*NDIM + i0+di];
    }
    for(int l=threadIdx.x; l<32*64; l+=256){
      int di = l>>6, df = l&63;
      Bs[di][df] = X1b[(size_t)(i0+di)*FDIM + f0+df];
    }
    __syncthreads();
#pragma unroll
    for(int dk=0;dk<32;dk++){
      float a[4], bb[4];
#pragma unroll
      for(int z=0;z<4;z++){ a[z]=As[dk][ty*4+z]; bb[z]=Bs[dk][tx*4+z]; }
#pragma unroll
      for(int p=0;p<4;p++)
#pragma unroll
        for(int q=0;q<4;q++) acc[p][q] += a[p]*bb[q];
    }
    __syncthreads();
  }
#pragma unroll
  for(int p=0;p<4;p++){
    size_t ro = ((size_t)b*NDIM + n0+ty*4+p)*FDIM + f0 + tx*4;
    float4 xr = *(const float4*)(X + ro);
    float4 o = { acc[p][0]+xr.x, acc[p][1]+xr.y, acc[p][2]+xr.z, acc[p][3]+xr.w };
    *(float4*)(outp + ro) = o;
  }
}

extern "C" void kernel_launch(void* const* d_in, const int* in_sizes, int n_in,
                              void* d_out, int out_size, void* d_ws, size_t ws_size,
                              hipStream_t stream) {
  (void)in_sizes; (void)n_in; (void)out_size; (void)ws_size;
  const float* nf  = (const float*)d_in[0];
  const int*   eidx= (const int*)d_in[1];
  const float* ew  = (const float*)d_in[2];
  const float* lng = (const float*)d_in[3];
  const float* lnb = (const float*)d_in[4];
  const float* w1  = (const float*)d_in[5];
  const float* b1  = (const float*)d_in[6];
  const float* w2  = (const float*)d_in[7];
  const float* b2  = (const float*)d_in[8];

  float* ws = (float*)d_ws;
  const size_t NN = (size_t)NDIM*NDIM;
  float* A   = ws;                               // B*N*N ; Laplacian -> stein LU factors fu+fm
  float* U   = A  + (size_t)BDIM*NN;             // B*N*N Householder vectors
  float* W   = U  + (size_t)BDIM*NN;             // B*N*N tridiag eigvecs -> full eigvecs Z
  float* X   = W  + (size_t)BDIM*NN;             // B*N*F layernorm output (residual)
  float* X1  = X  + (size_t)BDIM*NDIM*FDIM;      // B*N*F ; stein f1 scratch (PCH*NDIM = B*N*F exactly)
  float* dia = X1 + (size_t)BDIM*NDIM*FDIM;      // B*N
  float* off = dia + (size_t)BDIM*NDIM;          // B*N
  float* tau = off + (size_t)BDIM*NDIM;          // B*N
  float* lam = tau + (size_t)BDIM*NDIM;          // B*N
  float* dis = lam + (size_t)BDIM*NDIM;          // B*N
  float* hbf = dis + (size_t)BDIM*NDIM;          // B*H
  float* evb = hbf + (size_t)BDIM*HDIM;          // B*N
  int*   flag= (int*)(evb + (size_t)BDIM*NDIM);

  hipMemsetAsync(A, 0, (size_t)BDIM*NN*sizeof(float), stream);
  k_detect <<<1, 1024, 0, stream>>>((const unsigned*)eidx, flag);
  k_scatter<<<(BDIM*EDIM)/256, 256, 0, stream>>>(ew, eidx, flag, A);
  k_degree <<<(BDIM*NDIM)/4, 256, 0, stream>>>(A, dis);
  k_lap    <<<(unsigned)((size_t)BDIM*NN/256), 256, 0, stream>>>(A, dis);
  k_ln     <<<(BDIM*NDIM)/4, 256, 0, stream>>>(nf, lng, lnb, X);
  k_tridiag<<<BDIM, 512, 0, stream>>>(A, U, dia, off, tau);
  k_bisect <<<BDIM, 512, 0, stream>>>(dia, off, lam);
  k_mlp1   <<<dim3(HDIM/4, BDIM), 256, 0, stream>>>(lam, w1, b1, hbf);
  k_mlp2   <<<dim3(NDIM/4, BDIM), 256, 0, stream>>>(hbf, w2, b2, evb);
  for(int c=0;c<(BDIM*NDIM)/PCH;c++)
    k_stein<<<PCH/64, 64, 0, stream>>>(dia, off, lam, W, A /*fu+fm*/, X1 /*f1*/, c);
  k_mgs    <<<BDIM, 512, 0, stream>>>(lam, W);
  k_backt  <<<BDIM*32, 512, 0, stream>>>(W, U, tau);
  k_gemm1  <<<dim3(FDIM/64, NDIM/64, BDIM), 256, 0, stream>>>(W, X, evb, X1);
  k_gemm2  <<<dim3(FDIM/64, NDIM/64, BDIM), 256, 0, stream>>>(W, X1, X, (float*)d_out);
}

// Round 10
// 8622.720 us; speedup vs baseline: 1.4111x; 1.4111x over previous
//
#include <hip/hip_runtime.h>
#include <math.h>

#define BDIM 32
#define NDIM 512
#define FDIM 256
#define HDIM 1024
#define EDIM 8192
#define PCH  8192      // stein chunk: (b,j) pairs per pass; 2 passes (fu+fm in A, f1 in X1)
#define CLTH 1.2e-4f   // eigenvalue cluster threshold for MGS
#define NB   16        // panel width (tridiag + backt WY)
#define BCOLS 16       // backt slab columns

__device__ __forceinline__ float waveRedSum(float v){
#pragma unroll
  for(int o=32;o>0;o>>=1) v += __shfl_down(v,o,64);
  return v;
}

__device__ __forceinline__ float rnd_f(int g, int i){
  unsigned s = (unsigned)g*1315423911u ^ (unsigned)i*2654435761u;
  s ^= s>>13; s *= 2246822519u; s ^= s>>16;
  return (float)(s & 0xFFFF)*(1.f/65536.f) - 0.5f;
}

// ---------------- int64-vs-int32 edge index layout detection ----------------
__global__ __launch_bounds__(1024) void k_detect(const unsigned* __restrict__ e, int* __restrict__ flag){
  int t = threadIdx.x;
  float c = 0.f;
  for(int i=t;i<EDIM;i+=1024) if(e[2*i+1] != 0u) c += 1.f;
  c = waveRedSum(c);
  __shared__ float r[16];
  if((t&63)==0) r[t>>6]=c;
  __syncthreads();
  if(t==0){ float s=0; for(int z=0;z<16;z++) s+=r[z]; flag[0] = (s>64.f)?1:0; }
}

// ---------------- Laplacian assembly ----------------
__global__ __launch_bounds__(256) void k_scatter(const float* __restrict__ ew, const int* __restrict__ eidx,
                                                 const int* __restrict__ flag, float* __restrict__ A){
  int t = blockIdx.x*256 + threadIdx.x;           // B*E threads
  int b = t>>13, e = t&(EDIM-1);
  int i, j;
  if(flag[0]){ i = eidx[e]; j = eidx[EDIM+e]; }
  else       { i = eidx[2*e]; j = eidx[2*(EDIM+e)]; }  // little-endian int64 low words
  i &= 511; j &= 511;
  float w = ew[(size_t)b*EDIM + e];
  w = 0.5f*fminf(fmaxf(w,0.f),1.f);               // clip then build (A+A^T)/2 directly
  float* Ab = A + (size_t)b*NDIM*NDIM;
  atomicAdd(Ab + (size_t)i*NDIM + j, w);
  atomicAdd(Ab + (size_t)j*NDIM + i, w);
}

__global__ __launch_bounds__(256) void k_degree(const float* __restrict__ A, float* __restrict__ dis){
  int wid = threadIdx.x>>6, lane = threadIdx.x&63;
  int row = blockIdx.x*4 + wid;                   // b*N + i
  const float* Ar = A + (size_t)row*NDIM;
  float s = 0.f;
  for(int j=lane;j<NDIM;j+=64) s += Ar[j];
  s = waveRedSum(s);
  if(lane==0) dis[row] = rsqrtf(fmaxf(s, 1e-6f));
}

__global__ __launch_bounds__(256) void k_lap(float* __restrict__ A, const float* __restrict__ dis){
  size_t t = (size_t)blockIdx.x*256 + threadIdx.x;   // B*N*N
  size_t nn = (size_t)NDIM*NDIM;
  int b = (int)(t / nn); size_t rem = t % nn;
  int i = (int)(rem / NDIM), j = (int)(rem % NDIM);
  float v = -dis[b*NDIM+i]*dis[b*NDIM+j]*A[t];
  if(i==j) v += 1.f + 1e-6f;
  A[t] = v;
}

// ---------------- LayerNorm (stores pre-relu x; relu applied at GEMM load) ----------------
__global__ __launch_bounds__(256) void k_ln(const float* __restrict__ nf, const float* __restrict__ g,
                                            const float* __restrict__ be, float* __restrict__ X){
  int wid = threadIdx.x>>6, lane = threadIdx.x&63;
  int row = blockIdx.x*4 + wid;                   // b*N + n
  const float4* r4 = (const float4*)(nf + (size_t)row*FDIM);
  float4 v = r4[lane];
  float s  = v.x+v.y+v.z+v.w;
  float s2 = v.x*v.x+v.y*v.y+v.z*v.z+v.w*v.w;
  s = waveRedSum(s); s2 = waveRedSum(s2);
  s = __shfl(s,0,64); s2 = __shfl(s2,0,64);
  float mean = s*(1.f/FDIM);
  float var  = s2*(1.f/FDIM) - mean*mean;
  float inv  = rsqrtf(var + 1e-5f);
  float4 gg = ((const float4*)g)[lane];
  float4 bb = ((const float4*)be)[lane];
  float4 o;
  o.x = (v.x-mean)*inv*gg.x + bb.x;
  o.y = (v.y-mean)*inv*gg.y + bb.y;
  o.z = (v.z-mean)*inv*gg.z + bb.z;
  o.w = (v.w-mean)*inv*gg.w + bb.w;
  ((float4*)(X + (size_t)row*FDIM))[lane] = o;
}

// ---------------- LATRD-blocked Householder tridiagonalization (1 block / matrix, 512 thr) ----------------
// 4 barriers/column; Wp holds RAW pv (hh correction applied algebraically via hh_s/hprev);
// wave-parallel panel dots in symv phase; row-(k+1) prefetch; per-panel diagonal preload.
// R9 fix: barrier after LDS-scalar init (first-column sigma race) and before Bmat (dia-read race).
__global__ __launch_bounds__(512,1) void k_tridiag(float* __restrict__ A, float* __restrict__ U,
                                                   float* __restrict__ dia, float* __restrict__ off,
                                                   float* __restrict__ tau){
  const int b = blockIdx.x, t = threadIdx.x;
  float* Ab = A + (size_t)b*NDIM*NDIM;
  float* Ub = U + (size_t)b*NDIM*NDIM;
  __shared__ __align__(16) float Up[NB][NDIM];    // 32KB
  __shared__ __align__(16) float Wp[NB][NDIM];    // 32KB (raw pv during panel)
  __shared__ __align__(16) float ps[4][NDIM];     // 8KB symv row-group partials
  __shared__ float dW[NB], dU[NB], hh_s[NB], dg_s[NB];
  __shared__ float sig_s, pd_s, x0_s;
  const int lane = t&63, wid = t>>6;
  const int cc = t&127, rg = t>>7;                // 128 col-chunks x 4 row-groups
  if(t==0){ sig_s = 0.f; pd_s = 0.f; }
  __syncthreads();                                 // B0: init visible before first atomicAdd
  float hprev = 0.f, rnext = 0.f;

  for(int k0=0; k0<NDIM-2; k0+=NB){
    const int ne = (NB < NDIM-2-k0)? NB : (NDIM-2-k0);
    if(t<ne) dg_s[t] = Ab[(size_t)(k0+t)*NDIM + (k0+t)];   // stale diag (read post-B1+)
    for(int p=0;p<ne;p++){
      const int k = k0+p;
      // ---- P1: virtual row k (raw-Wp corrected) + sigma reduce ----
      float v = 0.f;
      if(t>k){
        v = (p==0)? Ab[(size_t)k*NDIM + t] : rnext;
        for(int q=0;q<p;q++){
          float hq = (q==p-1)? hprev : hh_s[q];
          float uqk = Up[q][k], wqk = Wp[q][k];
          v -= uqk*Wp[q][t] + (wqk - 2.f*hq*uqk)*Up[q][t];
        }
      }
      if(t==k+1) x0_s = v;
      float ssq = (t>=k+2)? v*v : 0.f;
      ssq = waveRedSum(ssq);
      if(lane==0) atomicAdd(&sig_s, ssq);
      __syncthreads();                               // B1: sigma & x0 ready
      // ---- P2: compute u (redundant scalar math on all threads) ----
      const float sigma = sig_s, x0 = x0_s;
      if(t==0) pd_s = 0.f;
      float tk = 0.f, inv = 0.f, beta = x0;
      if(sigma > 1e-26f){
        beta = -copysignf(sqrtf(x0*x0+sigma), x0);
        tk = (beta-x0)/beta; inv = 1.f/(x0-beta);
      }
      const float u_t = (t>=k+2)? v*inv : ((t==k+1 && sigma>1e-26f)? 1.f : 0.f);
      Up[p][t] = u_t;
      __syncthreads();                               // B2: u ready
      // ---- P3: prefetch next row + wave-parallel dots + symv ----
      if(t==0) sig_s = 0.f;
      if(p+1<ne) rnext = Ab[(size_t)(k+1)*NDIM + t]; // within-panel: stale A by design
      for(int q=wid; q<p; q+=8){                     // wave wid owns dots q, q+8
        float du=0.f, dwr=0.f;
        for(int l=lane; l<NDIM; l+=64){
          float up_ = Up[p][l];
          du  += Up[q][l]*up_;
          dwr += Wp[q][l]*up_;
        }
        du = waveRedSum(du); dwr = waveRedSum(dwr);
        if(lane==0){
          float hq = (q==p-1)? hprev : hh_s[q];
          dU[q] = du; dW[q] = dwr - hq*du;           // real w_q . u
        }
      }
      {
        float4 acc = {0.f,0.f,0.f,0.f};
        const int j0 = 4*cc;
        if(j0+3 > k){
          const float* basep = Ab + j0;
          const int ib0 = (k+1)&~31;                 // u[i]==0 for i<=k -> boundary-free
          const int i1 = rg*4, i2 = 16+rg*4;
          const float* ap = basep + (size_t)ib0*NDIM;
          float4 c0 = *(const float4*)(ap + (size_t)(i1  )*NDIM);
          float4 c1 = *(const float4*)(ap + (size_t)(i1+1)*NDIM);
          float4 c2 = *(const float4*)(ap + (size_t)(i1+2)*NDIM);
          float4 c3 = *(const float4*)(ap + (size_t)(i1+3)*NDIM);
          float4 d0 = *(const float4*)(ap + (size_t)(i2  )*NDIM);
          float4 d1 = *(const float4*)(ap + (size_t)(i2+1)*NDIM);
          float4 d2 = *(const float4*)(ap + (size_t)(i2+2)*NDIM);
          float4 d3 = *(const float4*)(ap + (size_t)(i2+3)*NDIM);
          for(int ib=ib0; ib<NDIM; ib+=32){
            float4 n0=c0,n1=c1,n2=c2,n3=c3,m0=d0,m1=d1,m2=d2,m3=d3;
            if(ib+32 < NDIM){
              const float* an = basep + (size_t)(ib+32)*NDIM;
              n0 = *(const float4*)(an + (size_t)(i1  )*NDIM);
              n1 = *(const float4*)(an + (size_t)(i1+1)*NDIM);
              n2 = *(const float4*)(an + (size_t)(i1+2)*NDIM);
              n3 = *(const float4*)(an + (size_t)(i1+3)*NDIM);
              m0 = *(const float4*)(an + (size_t)(i2  )*NDIM);
              m1 = *(const float4*)(an + (size_t)(i2+1)*NDIM);
              m2 = *(const float4*)(an + (size_t)(i2+2)*NDIM);
              m3 = *(const float4*)(an + (size_t)(i2+3)*NDIM);
            }
            float4 u1 = *(const float4*)&Up[p][ib+i1];
            float4 u2 = *(const float4*)&Up[p][ib+i2];
            acc.x += c0.x*u1.x + c1.x*u1.y + c2.x*u1.z + c3.x*u1.w
                   + d0.x*u2.x + d1.x*u2.y + d2.x*u2.z + d3.x*u2.w;
            acc.y += c0.y*u1.x + c1.y*u1.y + c2.y*u1.z + c3.y*u1.w
                   + d0.y*u2.x + d1.y*u2.y + d2.y*u2.z + d3.y*u2.w;
            acc.z += c0.z*u1.x + c1.z*u1.y + c2.z*u1.z + c3.z*u1.w
                   + d0.z*u2.x + d1.z*u2.y + d2.z*u2.z + d3.z*u2.w;
            acc.w += c0.w*u1.x + c1.w*u1.y + c2.w*u1.z + c3.w*u1.w
                   + d0.w*u2.x + d1.w*u2.y + d2.w*u2.z + d3.w*u2.w;
            c0=n0; c1=n1; c2=n2; c3=n3; d0=m0; d1=m1; d2=m2; d3=m3;
          }
        }
        *(float4*)&ps[rg][4*cc] = acc;
      }
      __syncthreads();                               // B3: ps + dots ready
      // ---- P4: pv (raw), pd reduce ----
      float py = ps[0][t]+ps[1][t]+ps[2][t]+ps[3][t];
      float corr = 0.f;
      for(int q=0;q<p;q++){
        float hq = (q==p-1)? hprev : hh_s[q];
        float duq = dU[q];
        corr += Up[q][t]*(dW[q] - hq*duq) + Wp[q][t]*duq;
      }
      float pv = tk*(py - corr);
      Wp[p][t] = pv;                                 // RAW (no hh yet)
      float pdp = waveRedSum(pv*u_t);
      if(lane==0) atomicAdd(&pd_s, pdp);
      if(t>k) Ub[(size_t)k*NDIM + (t-k-1)] = u_t;
      if(t==0){ off[(size_t)b*NDIM+k] = beta; tau[(size_t)b*NDIM+k] = tk; }
      __syncthreads();                               // B4: pd + raw pv ready
      // ---- P5 (no trailing barrier): dia (uses OLD hprev), then update hprev ----
      if(t==0){
        float dk = dg_s[p];
        for(int q=0;q<p;q++){
          float hq = (q==p-1)? hprev : hh_s[q];
          float uqk = Up[q][k];
          dk -= 2.f*uqk*(Wp[q][k] - hq*uqk);
        }
        dia[(size_t)b*NDIM+k] = dk;
      }
      hprev = 0.5f*tk*pd_s;
      if(t==0) hh_s[p] = hprev;
    }
    __syncthreads();                                 // Bfix: P5 dia reads done before Wp mutated
    // ---- materialize real w, then trailing rank-2*ne update ----
    for(int q=0;q<ne;q++){
      float hq = (q==ne-1)? hprev : hh_s[q];
      Wp[q][t] -= hq*Up[q][t];
    }
    __syncthreads();                                 // Bmat
    {
      const int r0 = k0+ne;
      const int rbase = r0 & ~15;                 // extra rows/cols never read again
      const int cstart = rbase>>2;
      if(cc >= cstart){
        const int j0 = 4*cc;
        for(int rt=rbase; rt<NDIM; rt+=16){
          const int i0 = rt + rg*4;
          float* a0 = Ab + (size_t)i0*NDIM + j0;
          float4 v0 = *(float4*)(a0);
          float4 v1 = *(float4*)(a0+NDIM);
          float4 v2 = *(float4*)(a0+2*NDIM);
          float4 v3 = *(float4*)(a0+3*NDIM);
          #pragma unroll 4
          for(int q=0;q<ne;q++){
            float4 Ui = *(const float4*)&Up[q][i0];
            float4 Wi = *(const float4*)&Wp[q][i0];
            float4 Uj = *(const float4*)&Up[q][j0];
            float4 Wj = *(const float4*)&Wp[q][j0];
            v0.x -= Ui.x*Wj.x + Wi.x*Uj.x; v0.y -= Ui.x*Wj.y + Wi.x*Uj.y; v0.z -= Ui.x*Wj.z + Wi.x*Uj.z; v0.w -= Ui.x*Wj.w + Wi.x*Uj.w;
            v1.x -= Ui.y*Wj.x + Wi.y*Uj.x; v1.y -= Ui.y*Wj.y + Wi.y*Uj.y; v1.z -= Ui.y*Wj.z + Wi.y*Uj.z; v1.w -= Ui.y*Wj.w + Wi.y*Uj.w;
            v2.x -= Ui.z*Wj.x + Wi.z*Uj.x; v2.y -= Ui.z*Wj.y + Wi.z*Uj.y; v2.z -= Ui.z*Wj.z + Wi.z*Uj.z; v2.w -= Ui.z*Wj.w + Wi.z*Uj.w;
            v3.x -= Ui.w*Wj.x + Wi.w*Uj.x; v3.y -= Ui.w*Wj.y + Wi.w*Uj.y; v3.z -= Ui.w*Wj.z + Wi.w*Uj.z; v3.w -= Ui.w*Wj.w + Wi.w*Uj.w;
          }
          *(float4*)(a0)        = v0;
          *(float4*)(a0+NDIM)   = v1;
          *(float4*)(a0+2*NDIM) = v2;
          *(float4*)(a0+3*NDIM) = v3;
        }
      }
    }
    __syncthreads();
  }
  if(t==0){
    dia[(size_t)b*NDIM+NDIM-2] = Ab[(size_t)(NDIM-2)*NDIM+NDIM-2];
    dia[(size_t)b*NDIM+NDIM-1] = Ab[(size_t)(NDIM-1)*NDIM+NDIM-1];
    off[(size_t)b*NDIM+NDIM-2] = Ab[(size_t)(NDIM-2)*NDIM+NDIM-1];
    off[(size_t)b*NDIM+NDIM-1] = 0.f;
    tau[(size_t)b*NDIM+NDIM-2]=0.f; tau[(size_t)b*NDIM+NDIM-1]=0.f;
  }
}

// ---------------- eigenvalues: Sturm bisection (thread j -> j-th smallest) ----------------
__global__ __launch_bounds__(512) void k_bisect(const float* __restrict__ dia, const float* __restrict__ off,
                                                float* __restrict__ lam){
  int b = blockIdx.x, t = threadIdx.x;
  __shared__ float ds[NDIM], e2[NDIM];
  __shared__ float red[16];
  __shared__ float slo, shi;
  ds[t] = dia[(size_t)b*NDIM+t];
  float ev = (t<NDIM-1)? off[(size_t)b*NDIM+t] : 0.f;
  e2[t] = ev*ev;
  __syncthreads();
  float el = (t>0)? sqrtf(e2[t-1]) : 0.f;
  float er = fabsf(ev);
  float lo = ds[t]-el-er, hi = ds[t]+el+er;
#pragma unroll
  for(int o=32;o>0;o>>=1){ lo = fminf(lo,__shfl_down(lo,o,64)); hi = fmaxf(hi,__shfl_down(hi,o,64)); }
  if((t&63)==0){ red[t>>6]=lo; red[8+(t>>6)]=hi; }
  __syncthreads();
  if(t==0){
    float L=red[0], H=red[8];
    for(int z=1;z<8;z++){ L=fminf(L,red[z]); H=fmaxf(H,red[8+z]); }
    slo = L-1e-3f; shi = H+1e-3f;
  }
  __syncthreads();
  float lo2 = slo, hi2 = shi;
  for(int it=0; it<30; ++it){
    float mid = 0.5f*(lo2+hi2);
    float q = ds[0]-mid; int c = (q<0.f)?1:0;
    for(int i=1;i<NDIM;i++){
      float dn = (fabsf(q)<1e-10f)? ((q<0.f)?-1e-10f:1e-10f) : q;
      q = ds[i]-mid - __fdividef(e2[i-1], dn);
      c += (q<0.f)?1:0;
    }
    if(c<=t) lo2=mid; else hi2=mid;
  }
  lam[(size_t)b*NDIM+t] = 0.5f*(lo2+hi2);
}

// ---------------- eigenvectors of T: inverse iteration; fu+fm in fac, s1 in xs ----------------
__global__ __launch_bounds__(64) void k_stein(const float* __restrict__ dia, const float* __restrict__ off,
                                              const float* __restrict__ lam, float* __restrict__ W,
                                              float* __restrict__ fac, float* __restrict__ xs, int chunk){
  int p = blockIdx.x*64 + threadIdx.x;            // 0..PCH-1
  int g = chunk*PCH + p;                           // global (b,j)
  int b = g >> 9, j = g & 511;
  __shared__ float ds[NDIM], es[NDIM];
  for(int i=threadIdx.x;i<NDIM;i+=64){ ds[i]=dia[(size_t)b*NDIM+i]; es[i]=off[(size_t)b*NDIM+i]; }
  __syncthreads();
  float lm = lam[(size_t)b*NDIM+j] + (float)((j%5)-2)*1.2e-7f;   // tiny split of identical shifts
  float* fu = fac + p;                              // reciprocal pivots 1/u
  float* fm = fac + (size_t)PCH*NDIM + p;           // mm encoded: +3.0 if row-swapped (|mm|<=1)
  float* f1a = xs + p;                              // s1 (running superdiag / an on swap)
  // ---- factor (T - lm I) = P L U, partial pivoting ----
  float ai = ds[0]-lm, bi = es[0];
  for(int ib=0; ib<NDIM-1; ib+=8){
    const int lim = (NDIM-1-ib < 8)? NDIM-1-ib : 8;
    float dsb[8], esb[8], enb[8];
    #pragma unroll
    for(int z=0;z<8;z++){
      int i = ib+z; bool vz = z<lim;
      dsb[z] = vz? ds[i+1] : 0.f;
      esb[z] = vz? es[i]   : 0.f;
      enb[z] = (vz && i<NDIM-2)? es[i+1] : 0.f;
    }
    #pragma unroll
    for(int z=0;z<8;z++){
      if(z<lim){
        int i = ib+z;
        float ci = esb[z], an = dsb[z]-lm, bn = enb[z];
        float uu, mmenc, s1;
        if(fabsf(ai) >= fabsf(ci)){
          float aa = (fabsf(ai)<1e-12f)? ((ai<0.f)?-1e-12f:1e-12f) : ai;
          float mm = __fdividef(ci, aa);
          uu=aa; mmenc=mm; s1=bi;
          ai = an - mm*bi; bi = bn;
        } else {
          float cch = (fabsf(ci)<1e-12f)? ((ci<0.f)?-1e-12f:1e-12f) : ci;
          float mm = __fdividef(ai, cch);
          uu=cch; mmenc=mm+3.f; s1=an;
          ai = bi - mm*an; bi = -mm*bn;
        }
        fu[(size_t)i*PCH]=__fdividef(1.f,uu);
        fm[(size_t)i*PCH]=mmenc;
        f1a[(size_t)i*PCH]=s1;
      }
    }
  }
  { float aa = (fabsf(ai)<1e-12f)? ((ai<0.f)?-1e-12f:1e-12f) : ai; fu[(size_t)(NDIM-1)*PCH]=__fdividef(1.f,aa); }
  float* Wb = W + (size_t)b*NDIM*NDIM + j;         // element i at Wb[i*NDIM]
  float scale = 1.f;
  for(int it=0; it<3; ++it){
    // ---- forward substitution, 8-deep prefetch ----
    float yi = (it==0)? rnd_f(g,0) : Wb[0]*scale;
    for(int ib=0; ib<NDIM-1; ib+=8){
      const int lim = (NDIM-1-ib < 8)? NDIM-1-ib : 8;
      float wn[8], me[8];
      #pragma unroll
      for(int z=0;z<8;z++){
        int i = ib+z; bool vz = z<lim;
        wn[z] = vz? ((it==0)? rnd_f(g,i+1) : Wb[(size_t)(i+1)*NDIM]*scale) : 0.f;
        me[z] = vz? fm[(size_t)i*PCH] : 0.f;
      }
      #pragma unroll
      for(int z=0;z<8;z++){
        if(z<lim){
          int i = ib+z;
          float enc = me[z]; bool sw = enc>1.5f; float mm = sw? enc-3.f : enc;
          float yn = wn[z];
          if(sw){ float tmp=yi; yi=yn; yn=tmp; }
          yn -= mm*yi;
          Wb[(size_t)i*NDIM] = yi;
          yi = yn;
        }
      }
    }
    // ---- backward substitution (division-free; f1 stored, f2 from flag) ----
    float nrm, xp1, xp2;
    {
      float xi = yi * fu[(size_t)(NDIM-1)*PCH];
      Wb[(size_t)(NDIM-1)*NDIM]=xi; nrm = xi*xi; xp2=0.f; xp1=xi;
    }
    for(int ib=NDIM-2; ib>=0; ib-=8){
      const int lim = (ib+1 < 8)? ib+1 : 8;
      float yv[8], ru[8], me[8], f1b[8];
      #pragma unroll
      for(int z=0;z<8;z++){
        int i = ib-z; bool vz = z<lim;
        yv[z]  = vz? Wb[(size_t)i*NDIM] : 0.f;
        ru[z]  = vz? fu[(size_t)i*PCH] : 0.f;
        me[z]  = vz? fm[(size_t)i*PCH] : 0.f;
        f1b[z] = vz? f1a[(size_t)i*PCH] : 0.f;
      }
      #pragma unroll
      for(int z=0;z<8;z++){
        if(z<lim){
          int i = ib-z;
          bool sw = me[z]>1.5f;
          float f2 = sw? ((i<NDIM-2)? es[i+1] : 0.f) : 0.f;
          float xi = (yv[z] - f1b[z]*xp1 - f2*xp2)*ru[z];
          Wb[(size_t)i*NDIM]=xi; nrm += xi*xi;
          xp2=xp1; xp1=xi;
        }
      }
    }
    scale = rsqrtf(fmaxf(nrm,1e-30f));
  }
  for(int ib=0; ib<NDIM; ib+=8){
    float vz[8];
    #pragma unroll
    for(int z=0;z<8;z++) vz[z] = Wb[(size_t)(ib+z)*NDIM];
    #pragma unroll
    for(int z=0;z<8;z++) Wb[(size_t)(ib+z)*NDIM] = vz[z]*scale;
  }
}

// ---------------- MGS inside eigenvalue clusters ----------------
__global__ __launch_bounds__(512) void k_mgs(const float* __restrict__ lam, float* __restrict__ W){
  int b = blockIdx.x, t = threadIdx.x;
  __shared__ int cstart[NDIM];
  __shared__ unsigned char brk[NDIM];
  __shared__ float red[8];
  __shared__ float sbc;
  const float* lb = lam + (size_t)b*NDIM;
  float* Wb = W + (size_t)b*NDIM*NDIM;
  brk[t] = (t==0)? 1 : ((lb[t]-lb[t-1] > CLTH)? 1 : 0);
  __syncthreads();
  if(t==0){ int s=0; for(int j=0;j<NDIM;j++){ if(brk[j]) s=j; cstart[j]=s; } }
  __syncthreads();
  for(int j=1;j<NDIM;j++){
    int s = cstart[j];
    if(s==j) continue;                             // uniform branch
    for(int q=s;q<j;q++){
      float pd = 0.f;
      pd = Wb[(size_t)t*NDIM+q]*Wb[(size_t)t*NDIM+j];
      pd = waveRedSum(pd);
      if((t&63)==0) red[t>>6]=pd;
      __syncthreads();
      if(t==0){ float s2=0; for(int z=0;z<8;z++) s2+=red[z]; sbc=s2; }
      __syncthreads();
      float dt = sbc;
      Wb[(size_t)t*NDIM+j] -= dt*Wb[(size_t)t*NDIM+q];
      __syncthreads();
    }
    float v = Wb[(size_t)t*NDIM+j];
    float pn = waveRedSum(v*v);
    if((t&63)==0) red[t>>6]=pn;
    __syncthreads();
    if(t==0){ float s2=0; for(int z=0;z<8;z++) s2+=red[z]; sbc=s2; }
    __syncthreads();
    Wb[(size_t)t*NDIM+j] = v*rsqrtf(fmaxf(sbc,1e-20f));
    __syncthreads();
  }
}

// ---------------- back-transform Z = H0..H509 * W ; blocked LARFB (compact-WY), 16-col slabs ----------------
__global__ __launch_bounds__(512,4) void k_backt(float* __restrict__ W, const float* __restrict__ U,
                                                 const float* __restrict__ tau){
  __shared__ float S[NDIM][BCOLS+1];     // 34816 B
  __shared__ float Up[NB][516];          // 33024 B
  __shared__ float Gp[NB][NB+1];         // Gram v_s.v_j (s<j)
  __shared__ float Tm[NB][NB+1];         // T upper-triangular
  __shared__ float Yp[2][NB][NB+1];      // Y = V^T S partials
  __shared__ float Z16[NB][NB+1];        // Z = T Y
  __shared__ float tls[NB];
  const int t = threadIdx.x;
  int b = blockIdx.x >> 5, slab = blockIdx.x & 31;
  int c0 = slab*BCOLS;
  float* Wb = W + (size_t)b*NDIM*NDIM;
  const float* Ub = U + (size_t)b*NDIM*NDIM;
  for(int l=t; l<NDIM*BCOLS; l+=512){
    int i = l>>4, c = l&15;
    S[i][c] = Wb[(size_t)i*NDIM + c0 + c];
  }
  __syncthreads();
  for(int k0 = ((NDIM-3)/NB)*NB; k0>=0; k0-=NB){
    for(int l=t; l<NB*NDIM; l+=512){
      int q = l>>9, i = l&511;
      int k = k0+q;
      float v = 0.f;
      if(k < NDIM-2 && i > k) v = Ub[(size_t)k*NDIM + (i-k-1)];
      Up[q][i] = v;
    }
    if(t<NB) tls[t] = (k0+t < NDIM-2)? tau[(size_t)b*NDIM + k0 + t] : 0.f;
    if(t<NB*(NB+1)) ((float*)Gp)[t] = 0.f;
    __syncthreads();                                  // P1: V, tau ready; G zeroed
    if(t < 480){
      int pp = t>>2, sub = t&3;
      int pj=1, pr=pp;
      while(pr >= pj){ pr -= pj; pj++; }
      int s = pr, jj = pj;                            // s < jj, jj in 1..15
      float acc = 0.f;
      for(int i=k0+1+sub; i<NDIM; i+=4) acc += Up[s][i]*Up[jj][i];
      atomicAdd(&Gp[s][jj], acc);
    }
    __syncthreads();                                  // P2: G ready
    if(t < 16){
      int a = t;
      for(int j=0;j<NB;j++){
        float v;
        if(a==j) v = tls[j];
        else if(a<j){
          float s2 = 0.f;
          for(int s=a; s<j; s++) s2 += Tm[a][s]*Gp[s][j];
          v = -tls[j]*s2;
        } else v = 0.f;
        Tm[a][j] = v;
      }
    }
    __syncthreads();                                  // P3: T ready
    {
      int q=(t>>4)&15, c=t&15, half=t>>8;
      float a0=0.f, a1=0.f;
      int i = k0+1+half;
      for(; i+2<NDIM; i+=4){ a0 += Up[q][i]*S[i][c]; a1 += Up[q][i+2]*S[i+2][c]; }
      for(; i<NDIM; i+=2) a0 += Up[q][i]*S[i][c];
      Yp[half][q][c] = a0+a1;
    }
    __syncthreads();                                  // P4: Y ready
    if(t < 256){
      int a=t>>4, c=t&15;
      float acc=0.f;
      #pragma unroll
      for(int j=0;j<NB;j++) acc += Tm[a][j]*(Yp[0][j][c]+Yp[1][j][c]);
      Z16[a][c]=acc;
    }
    __syncthreads();                                  // P5: Z ready
    {
      int rg=t>>4, c=t&15;
      float zc[NB];
      #pragma unroll
      for(int q=0;q<NB;q++) zc[q]=Z16[q][c];
      for(int i=k0+1+rg; i<NDIM; i+=32){
        float s2=0.f;
        #pragma unroll
        for(int q=0;q<NB;q++) s2 += Up[q][i]*zc[q];
        S[i][c] -= s2;
      }
    }
    __syncthreads();                                  // P6: S updated; safe to reload V
  }
  for(int l=t; l<NDIM*BCOLS; l+=512){
    int i = l>>4, c = l&15;
    Wb[(size_t)i*NDIM + c0 + c] = S[i][c];
  }
}

// ---------------- eigenvalue MLP ----------------
__global__ __launch_bounds__(256) void k_mlp1(const float* __restrict__ lam, const float* __restrict__ w1,
                                              const float* __restrict__ b1, float* __restrict__ h){
  int wid = threadIdx.x>>6, lane = threadIdx.x&63;
  int j = blockIdx.x*4 + wid, b = blockIdx.y;
  const float* lb = lam + (size_t)b*NDIM;
  const float* wr = w1 + (size_t)j*NDIM;
  float acc = 0.f;
  for(int k=lane;k<NDIM;k+=64) acc += lb[k]*wr[k];
  acc = waveRedSum(acc);
  if(lane==0) h[(size_t)b*HDIM + j] = fmaxf(acc + b1[j], 0.f);
}
__global__ __launch_bounds__(256) void k_mlp2(const float* __restrict__ h, const float* __restrict__ w2,
                                              const float* __restrict__ b2, float* __restrict__ evb){
  int wid = threadIdx.x>>6, lane = threadIdx.x&63;
  int n = blockIdx.x*4 + wid, b = blockIdx.y;
  const float* hb = h + (size_t)b*HDIM;
  const float* wr = w2 + (size_t)n*HDIM;
  float acc = 0.f;
  for(int k=lane;k<HDIM;k+=64) acc += hb[k]*wr[k];
  acc = waveRedSum(acc);
  if(lane==0) evb[(size_t)b*NDIM + n] = acc + b2[n];
}

// ---------------- GEMM1: X1[i][f] = ev[i] * sum_n Z[n][i]*relu(X[n][f]) ----------------
__global__ __launch_bounds__(256) void k_gemm1(const float* __restrict__ Z, const float* __restrict__ X,
                                               const float* __restrict__ evb, float* __restrict__ X1){
  int b = blockIdx.z;
  int i0 = blockIdx.y*64, f0 = blockIdx.x*64;
  const float* Zb = Z + (size_t)b*NDIM*NDIM;
  const float* Xb = X + (size_t)b*NDIM*FDIM;
  __shared__ float As[32][65], Bs[32][65];
  int tx = threadIdx.x & 15, ty = threadIdx.x >> 4;
  float acc[4][4] = {};
  for(int n0=0;n0<NDIM;n0+=32){
    for(int l=threadIdx.x; l<32*64; l+=256){
      int dn = l>>6, dc = l&63;
      As[dn][dc] = Zb[(size_t)(n0+dn)*NDIM + i0+dc];
      Bs[dn][dc] = fmaxf(Xb[(size_t)(n0+dn)*FDIM + f0+dc], 0.f);
    }
    __syncthreads();
#pragma unroll
    for(int dn=0;dn<32;dn++){
      float a[4], bb[4];
#pragma unroll
      for(int z=0;z<4;z++){ a[z]=As[dn][ty*4+z]; bb[z]=Bs[dn][tx*4+z]; }
#pragma unroll
      for(int p=0;p<4;p++)
#pragma unroll
        for(int q=0;q<4;q++) acc[p][q] += a[p]*bb[q];
    }
    __syncthreads();
  }
#pragma unroll
  for(int p=0;p<4;p++){
    int i = i0 + ty*4 + p;
    float s = evb[(size_t)b*NDIM + i];
    float4 o = { acc[p][0]*s, acc[p][1]*s, acc[p][2]*s, acc[p][3]*s };
    *(float4*)(X1 + ((size_t)b*NDIM + i)*FDIM + f0 + tx*4) = o;
  }
}

// ---------------- GEMM2: out[n][f] = X[n][f] + sum_i Z[n][i]*X1[i][f] ----------------
__global__ __launch_bounds__(256) void k_gemm2(const float* __restrict__ Z, const float* __restrict__ X1,
                                               const float* __restrict__ X, float* __restrict__ outp){
  int b = blockIdx.z;
  int n0 = blockIdx.y*64, f0 = blockIdx.x*64;
  const float* Zb = Z + (size_t)b*NDIM*NDIM;
  const float* X1b = X1 + (size_t)b*NDIM*FDIM;
  __shared__ float As[32][65], Bs[32][65];
  int tx = threadIdx.x & 15, ty = threadIdx.x >> 4;
  float acc[4][4] = {};
  for(int i0=0;i0<NDIM;i0+=32){
    for(int l=threadIdx.x; l<32*64; l+=256){
      int di = l&31, dn = l>>5;
      As[di][dn] = Zb[(size_t)(n0+dn)*NDIM + i0+di];
    }
    for(int l=threadIdx.x; l<32*64; l+=256){
      int di = l>>6, df = l&63;
      Bs[di][df] = X1b[(size_t)(i0+di)*FDIM + f0+df];
    }
    __syncthreads();
#pragma unroll
    for(int dk=0;dk<32;dk++){
      float a[4], bb[4];
#pragma unroll
      for(int z=0;z<4;z++){ a[z]=As[dk][ty*4+z]; bb[z]=Bs[dk][tx*4+z]; }
#pragma unroll
      for(int p=0;p<4;p++)
#pragma unroll
        for(int q=0;q<4;q++) acc[p][q] += a[p]*bb[q];
    }
    __syncthreads();
  }
#pragma unroll
  for(int p=0;p<4;p++){
    size_t ro = ((size_t)b*NDIM + n0+ty*4+p)*FDIM + f0 + tx*4;
    float4 xr = *(const float4*)(X + ro);
    float4 o = { acc[p][0]+xr.x, acc[p][1]+xr.y, acc[p][2]+xr.z, acc[p][3]+xr.w };
    *(float4*)(outp + ro) = o;
  }
}

extern "C" void kernel_launch(void* const* d_in, const int* in_sizes, int n_in,
                              void* d_out, int out_size, void* d_ws, size_t ws_size,
                              hipStream_t stream) {
  (void)in_sizes; (void)n_in; (void)out_size; (void)ws_size;
  const float* nf  = (const float*)d_in[0];
  const int*   eidx= (const int*)d_in[1];
  const float* ew  = (const float*)d_in[2];
  const float* lng = (const float*)d_in[3];
  const float* lnb = (const float*)d_in[4];
  const float* w1  = (const float*)d_in[5];
  const float* b1  = (const float*)d_in[6];
  const float* w2  = (const float*)d_in[7];
  const float* b2  = (const float*)d_in[8];

  float* ws = (float*)d_ws;
  const size_t NN = (size_t)NDIM*NDIM;
  float* A   = ws;                               // B*N*N ; Laplacian -> stein LU factors fu+fm
  float* U   = A  + (size_t)BDIM*NN;             // B*N*N Householder vectors
  float* W   = U  + (size_t)BDIM*NN;             // B*N*N tridiag eigvecs -> full eigvecs Z
  float* X   = W  + (size_t)BDIM*NN;             // B*N*F layernorm output (residual)
  float* X1  = X  + (size_t)BDIM*NDIM*FDIM;      // B*N*F ; stein f1 scratch (PCH*NDIM = B*N*F exactly)
  float* dia = X1 + (size_t)BDIM*NDIM*FDIM;      // B*N
  float* off = dia + (size_t)BDIM*NDIM;          // B*N
  float* tau = off + (size_t)BDIM*NDIM;          // B*N
  float* lam = tau + (size_t)BDIM*NDIM;          // B*N
  float* dis = lam + (size_t)BDIM*NDIM;          // B*N
  float* hbf = dis + (size_t)BDIM*NDIM;          // B*H
  float* evb = hbf + (size_t)BDIM*HDIM;          // B*N
  int*   flag= (int*)(evb + (size_t)BDIM*NDIM);

  hipMemsetAsync(A, 0, (size_t)BDIM*NN*sizeof(float), stream);
  k_detect <<<1, 1024, 0, stream>>>((const unsigned*)eidx, flag);
  k_scatter<<<(BDIM*EDIM)/256, 256, 0, stream>>>(ew, eidx, flag, A);
  k_degree <<<(BDIM*NDIM)/4, 256, 0, stream>>>(A, dis);
  k_lap    <<<(unsigned)((size_t)BDIM*NN/256), 256, 0, stream>>>(A, dis);
  k_ln     <<<(BDIM*NDIM)/4, 256, 0, stream>>>(nf, lng, lnb, X);
  k_tridiag<<<BDIM, 512, 0, stream>>>(A, U, dia, off, tau);
  k_bisect <<<BDIM, 512, 0, stream>>>(dia, off, lam);
  k_mlp1   <<<dim3(HDIM/4, BDIM), 256, 0, stream>>>(lam, w1, b1, hbf);
  k_mlp2   <<<dim3(NDIM/4, BDIM), 256, 0, stream>>>(hbf, w2, b2, evb);
  for(int c=0;c<(BDIM*NDIM)/PCH;c++)
    k_stein<<<PCH/64, 64, 0, stream>>>(dia, off, lam, W, A /*fu+fm*/, X1 /*f1*/, c);
  k_mgs    <<<BDIM, 512, 0, stream>>>(lam, W);
  k_backt  <<<BDIM*32, 512, 0, stream>>>(W, U, tau);
  k_gemm1  <<<dim3(FDIM/64, NDIM/64, BDIM), 256, 0, stream>>>(W, X, evb, X1);
  k_gemm2  <<<dim3(FDIM/64, NDIM/64, BDIM), 256, 0, stream>>>(W, X1, X, (float*)d_out);
}